// Round 6
// baseline (226.177 us; speedup 1.0000x reference)
//
#include <hip/hip_runtime.h>
#include <hip/hip_cooperative_groups.h>
#include <cfloat>
#include <climits>

namespace cg = cooperative_groups;

#define TT 1024
#define BB 16
#define DD 512
#define VV 1000
#define CHUNK 16             // output rows (s values) per block in phase 2
#define NCHUNK (TT / CHUNK)  // 64
#define KROWS (CHUNK / 2)    // 8 rows per 128-thread slot
#define GRID (BB * NCHUNK)   // 1024 blocks; == (T*B)/16 argmax rows per block

// Single cooperative kernel: phase 1 argmax -> grid.sync -> phase 2 seg+compress.
// Removes the second kernel launch (gap + tail drain were the only levers that
// have empirically moved total time).
__global__ void __launch_bounds__(256) mega_kernel(
        const float* __restrict__ logit,
        const unsigned char* __restrict__ padding,
        const float* __restrict__ rep,
        int* labels,
        float* __restrict__ out, float* __restrict__ out_pad) {
    int tid  = threadIdx.x;              // 0..255
    int lane = tid & 63, wid = tid >> 6; // 4 waves

    // ---------------- phase 1: argmax, 16 rows/block (4 per wave) ----------
    {
        int base_gw = blockIdx.x * 16 + wid * 4;     // gw = t*B + b
        for (int r = 0; r < 4; ++r) {
            int gw = base_gw + r;
            const float4* row = (const float4*)(logit + (size_t)gw * VV);
            float best = -FLT_MAX;
            int   bidx = INT_MAX;
            for (int i = lane; i < VV / 4; i += 64) {   // 250 float4 per row
                float4 v = row[i];
                int bse = i * 4;
                if (v.x > best) { best = v.x; bidx = bse;     }
                if (v.y > best) { best = v.y; bidx = bse + 1; }
                if (v.z > best) { best = v.z; bidx = bse + 2; }
                if (v.w > best) { best = v.w; bidx = bse + 3; }
            }
            for (int off = 32; off; off >>= 1) {        // first-index tie-break
                float ov = __shfl_xor(best, off);
                int   oi = __shfl_xor(bidx, off);
                if (ov > best || (ov == best && oi < bidx)) { best = ov; bidx = oi; }
            }
            if (lane == 0) {
                int t = gw / BB, b = gw % BB;           // logit layout (T,B,V)
                labels[b * TT + t] = bidx;              // store as (B,T)
            }
        }
    }
    __threadfence();            // device-scope visibility across XCDs
    cg::this_grid().sync();

    // ---------------- phase 2: seg scan + compress --------------------------
    int b = blockIdx.x / NCHUNK;
    int c = blockIdx.x % NCHUNK;
    int t0 = tid * 4;

    __shared__ int   wtot[4];
    __shared__ int   cnt_s[TT];
    __shared__ int   start_s[TT];
    __shared__ float w_s[TT];

    // change flags for 4 consecutive t
    int4 lab4 = *(const int4*)(labels + b * TT + t0);
    int prev  = (t0 > 0) ? labels[b * TT + t0 - 1] : -1;
    uchar4 p4 = *(const uchar4*)(padding + b * TT + t0);
    int v0 = !p4.x, v1 = !p4.y, v2 = !p4.z, v3 = !p4.w;
    int c0 = v0 && (lab4.x != prev);
    int c1 = v1 && (lab4.y != lab4.x);
    int c2 = v2 && (lab4.z != lab4.y);
    int c3 = v3 && (lab4.w != lab4.z);
    int l0 = c0, l1 = l0 + c1, l2 = l1 + c2, l3 = l2 + c3;

    // wave inclusive scan of per-thread totals
    int x = l3;
    for (int off = 1; off < 64; off <<= 1) {
        int y = __shfl_up(x, off);
        if (lane >= off) x += y;
    }
    if (lane == 63) wtot[wid] = x;
    cnt_s[t0] = 0; cnt_s[t0 + 1] = 0; cnt_s[t0 + 2] = 0; cnt_s[t0 + 3] = 0;
    __syncthreads();
    int woff = 0;
    #pragma unroll
    for (int i = 0; i < 4; ++i) if (i < wid) woff += wtot[i];
    int ns   = wtot[0] + wtot[1] + wtot[2] + wtot[3];
    int excl = woff + x - l3;

    int s0 = excl + l0 - 1, s1 = excl + l1 - 1, s2 = excl + l2 - 1, s3 = excl + l3 - 1;
    if (c0) start_s[s0] = t0;
    if (c1) start_s[s1] = t0 + 1;
    if (c2) start_s[s2] = t0 + 2;
    if (c3) start_s[s3] = t0 + 3;
    if (v0 && s0 >= 0) atomicAdd(&cnt_s[s0], 1);
    if (v1 && s1 >= 0) atomicAdd(&cnt_s[s1], 1);
    if (v2 && s2 >= 0) atomicAdd(&cnt_s[s2], 1);
    if (v3 && s3 >= 0) atomicAdd(&cnt_s[s3], 1);
    __syncthreads();
    w_s[t0]     = (v0 && s0 >= 0) ? (1.0f / (float)cnt_s[s0]) : 0.0f;
    w_s[t0 + 1] = (v1 && s1 >= 0) ? (1.0f / (float)cnt_s[s1]) : 0.0f;
    w_s[t0 + 2] = (v2 && s2 >= 0) ? (1.0f / (float)cnt_s[s2]) : 0.0f;
    w_s[t0 + 3] = (v3 && s3 >= 0) ? (1.0f / (float)cnt_s[s3]) : 0.0f;

    if (c == 0) {   // one chunk per batch emits the new padding mask
        float4 pm;
        pm.x = (t0     >= ns) ? 1.0f : 0.0f;
        pm.y = (t0 + 1 >= ns) ? 1.0f : 0.0f;
        pm.z = (t0 + 2 >= ns) ? 1.0f : 0.0f;
        pm.w = (t0 + 3 >= ns) ? 1.0f : 0.0f;
        *(float4*)(out_pad + b * TT + t0) = pm;
    }
    __syncthreads();

    // compress 16 rows: 2 slots of 128 threads, 8 rows each, ILP=8
    int sub = tid >> 7;                   // row slot 0/1
    int dq  = tid & 127;                  // float4 index within D=512
    const float4* rep4 = (const float4*)rep;

    int    st[KROWS];
    int    en[KROWS];
    float4 rv[KROWS];
    bool   ok[KROWS];
    #pragma unroll
    for (int k = 0; k < KROWS; ++k) {     // 8 independent first-t loads in flight
        int s = c * CHUNK + sub + 2 * k;
        ok[k] = (s < ns);
        int t1 = ok[k] ? start_s[s] : 0;
        st[k] = t1;
        en[k] = ok[k] ? ((s + 1 < ns) ? start_s[s + 1] : TT) : 0;
        if (ok[k]) rv[k] = rep4[((size_t)t1 * BB + b) * (DD / 4) + dq];
    }
    #pragma unroll
    for (int k = 0; k < KROWS; ++k) {
        int s = c * CHUNK + sub + 2 * k;
        float4 acc = make_float4(0.f, 0.f, 0.f, 0.f);
        if (ok[k]) {
            float ww = w_s[st[k]];        // segment start is always valid (w>0)
            acc.x = ww * rv[k].x; acc.y = ww * rv[k].y;
            acc.z = ww * rv[k].z; acc.w = ww * rv[k].w;
            for (int t = st[k] + 1; t < en[k]; ++t) {   // rare: len>1 segments
                float w2 = w_s[t];
                if (w2 != 0.0f) {
                    float4 rv2 = rep4[((size_t)t * BB + b) * (DD / 4) + dq];
                    acc.x += w2 * rv2.x; acc.y += w2 * rv2.y;
                    acc.z += w2 * rv2.z; acc.w += w2 * rv2.w;
                }
            }
        }
        ((float4*)out)[((size_t)s * BB + b) * (DD / 4) + dq] = acc;  // zeros past ns
    }
}

extern "C" void kernel_launch(void* const* d_in, const int* in_sizes, int n_in,
                              void* d_out, int out_size, void* d_ws, size_t ws_size,
                              hipStream_t stream) {
    const float* rep            = (const float*)d_in[0];
    const float* logit          = (const float*)d_in[1];
    const unsigned char* paddng = (const unsigned char*)d_in[2];

    float* out     = (float*)d_out;
    float* out_pad = out + (size_t)TT * BB * DD;     // second output: (B,T) mask

    int* labels = (int*)d_ws;                        // B*T int = 64 KiB

    void* args[] = { (void*)&logit, (void*)&paddng, (void*)&rep,
                     (void*)&labels, (void*)&out, (void*)&out_pad };
    hipLaunchCooperativeKernel((const void*)mega_kernel, dim3(GRID), dim3(256),
                               args, 0, stream);
}

// Round 7
// 82.719 us; speedup vs baseline: 2.7343x; 2.7343x over previous
//
#include <hip/hip_runtime.h>
#include <cfloat>
#include <climits>

#define TT 1024
#define BB 16
#define DD 512
#define VV 1000
#define CHUNK 16             // timesteps argmax'd AND output rows compressed per block
#define NCHUNK (TT / CHUNK)  // 64 blocks per batch
#define KROWS (CHUNK / 2)    // 8 rows per 128-thread slot

// Single kernel, per-batch software barrier. Block (b,c): phase 1 computes
// argmax labels for t in [c*16, c*16+16) of batch b; arrive-wait on batch b's
// counter (64 blocks); phase 2 scans batch b's labels and compresses its 16
// output rows. No global sync; batches proceed independently.
__global__ void __launch_bounds__(256) fused_all_kernel(
        const float* __restrict__ logit,
        const unsigned char* __restrict__ padding,
        const float* __restrict__ rep,
        int* labels, int* barriers,
        float* __restrict__ out, float* __restrict__ out_pad) {
    int b = blockIdx.x / NCHUNK;
    int c = blockIdx.x % NCHUNK;
    int tid  = threadIdx.x;              // 0..255
    int lane = tid & 63, wid = tid >> 6; // 4 waves

    // ---------------- phase 1: argmax for this block's 16 timesteps ---------
    {
        int tbase = c * CHUNK + wid * 4;
        for (int r = 0; r < 4; ++r) {
            int t = tbase + r;
            const float4* row = (const float4*)(logit + ((size_t)t * BB + b) * VV);
            float best = -FLT_MAX;
            int   bidx = INT_MAX;
            for (int i = lane; i < VV / 4; i += 64) {   // 250 float4 per row
                float4 v = row[i];
                int bse = i * 4;
                if (v.x > best) { best = v.x; bidx = bse;     }
                if (v.y > best) { best = v.y; bidx = bse + 1; }
                if (v.z > best) { best = v.z; bidx = bse + 2; }
                if (v.w > best) { best = v.w; bidx = bse + 3; }
            }
            for (int off = 32; off; off >>= 1) {        // first-index tie-break
                float ov = __shfl_xor(best, off);
                int   oi = __shfl_xor(bidx, off);
                if (ov > best || (ov == best && oi < bidx)) { best = ov; bidx = oi; }
            }
            if (lane == 0) labels[b * TT + t] = bidx;   // (B,T) layout
        }
    }

    // ---------------- per-batch arrive-wait barrier (64 blocks) -------------
    if (tid == 0) {
        __threadfence();                                 // release labels (device scope)
        int* bar = barriers + b * 32;                    // 128B-strided counters
        __hip_atomic_fetch_add(bar, 1, __ATOMIC_RELEASE, __HIP_MEMORY_SCOPE_AGENT);
        while (__hip_atomic_load(bar, __ATOMIC_ACQUIRE, __HIP_MEMORY_SCOPE_AGENT) < NCHUNK)
            __builtin_amdgcn_s_sleep(2);
    }
    __syncthreads();

    // ---------------- phase 2: seg scan + compress --------------------------
    int t0 = tid * 4;

    __shared__ int   wtot[4];
    __shared__ int   cnt_s[TT];
    __shared__ int   start_s[TT];
    __shared__ float w_s[TT];

    int4 lab4 = *(const int4*)(labels + b * TT + t0);
    int prev  = (t0 > 0) ? labels[b * TT + t0 - 1] : -1;
    uchar4 p4 = *(const uchar4*)(padding + b * TT + t0);
    int v0 = !p4.x, v1 = !p4.y, v2 = !p4.z, v3 = !p4.w;
    int c0 = v0 && (lab4.x != prev);
    int c1 = v1 && (lab4.y != lab4.x);
    int c2 = v2 && (lab4.z != lab4.y);
    int c3 = v3 && (lab4.w != lab4.z);
    int l0 = c0, l1 = l0 + c1, l2 = l1 + c2, l3 = l2 + c3;

    int x = l3;
    for (int off = 1; off < 64; off <<= 1) {
        int y = __shfl_up(x, off);
        if (lane >= off) x += y;
    }
    if (lane == 63) wtot[wid] = x;
    cnt_s[t0] = 0; cnt_s[t0 + 1] = 0; cnt_s[t0 + 2] = 0; cnt_s[t0 + 3] = 0;
    __syncthreads();
    int woff = 0;
    #pragma unroll
    for (int i = 0; i < 4; ++i) if (i < wid) woff += wtot[i];
    int ns   = wtot[0] + wtot[1] + wtot[2] + wtot[3];
    int excl = woff + x - l3;

    int s0 = excl + l0 - 1, s1 = excl + l1 - 1, s2 = excl + l2 - 1, s3 = excl + l3 - 1;
    if (c0) start_s[s0] = t0;
    if (c1) start_s[s1] = t0 + 1;
    if (c2) start_s[s2] = t0 + 2;
    if (c3) start_s[s3] = t0 + 3;
    if (v0 && s0 >= 0) atomicAdd(&cnt_s[s0], 1);
    if (v1 && s1 >= 0) atomicAdd(&cnt_s[s1], 1);
    if (v2 && s2 >= 0) atomicAdd(&cnt_s[s2], 1);
    if (v3 && s3 >= 0) atomicAdd(&cnt_s[s3], 1);
    __syncthreads();
    w_s[t0]     = (v0 && s0 >= 0) ? (1.0f / (float)cnt_s[s0]) : 0.0f;
    w_s[t0 + 1] = (v1 && s1 >= 0) ? (1.0f / (float)cnt_s[s1]) : 0.0f;
    w_s[t0 + 2] = (v2 && s2 >= 0) ? (1.0f / (float)cnt_s[s2]) : 0.0f;
    w_s[t0 + 3] = (v3 && s3 >= 0) ? (1.0f / (float)cnt_s[s3]) : 0.0f;

    if (c == 0) {   // one chunk per batch emits the new padding mask
        float4 pm;
        pm.x = (t0     >= ns) ? 1.0f : 0.0f;
        pm.y = (t0 + 1 >= ns) ? 1.0f : 0.0f;
        pm.z = (t0 + 2 >= ns) ? 1.0f : 0.0f;
        pm.w = (t0 + 3 >= ns) ? 1.0f : 0.0f;
        *(float4*)(out_pad + b * TT + t0) = pm;
    }
    __syncthreads();

    // compress 16 rows: 2 slots of 128 threads, 8 rows each, ILP=8
    int sub = tid >> 7;                   // row slot 0/1
    int dq  = tid & 127;                  // float4 index within D=512
    const float4* rep4 = (const float4*)rep;

    int    st[KROWS];
    int    en[KROWS];
    float4 rv[KROWS];
    bool   ok[KROWS];
    #pragma unroll
    for (int k = 0; k < KROWS; ++k) {     // 8 independent first-t loads in flight
        int s = c * CHUNK + sub + 2 * k;
        ok[k] = (s < ns);
        int t1 = ok[k] ? start_s[s] : 0;
        st[k] = t1;
        en[k] = ok[k] ? ((s + 1 < ns) ? start_s[s + 1] : TT) : 0;
        if (ok[k]) rv[k] = rep4[((size_t)t1 * BB + b) * (DD / 4) + dq];
    }
    #pragma unroll
    for (int k = 0; k < KROWS; ++k) {
        int s = c * CHUNK + sub + 2 * k;
        float4 acc = make_float4(0.f, 0.f, 0.f, 0.f);
        if (ok[k]) {
            float ww = w_s[st[k]];        // segment start is always valid (w>0)
            acc.x = ww * rv[k].x; acc.y = ww * rv[k].y;
            acc.z = ww * rv[k].z; acc.w = ww * rv[k].w;
            for (int t = st[k] + 1; t < en[k]; ++t) {   // rare: len>1 segments
                float w2 = w_s[t];
                if (w2 != 0.0f) {
                    float4 rv2 = rep4[((size_t)t * BB + b) * (DD / 4) + dq];
                    acc.x += w2 * rv2.x; acc.y += w2 * rv2.y;
                    acc.z += w2 * rv2.z; acc.w += w2 * rv2.w;
                }
            }
        }
        ((float4*)out)[((size_t)s * BB + b) * (DD / 4) + dq] = acc;  // zeros past ns
    }
}

extern "C" void kernel_launch(void* const* d_in, const int* in_sizes, int n_in,
                              void* d_out, int out_size, void* d_ws, size_t ws_size,
                              hipStream_t stream) {
    const float* rep            = (const float*)d_in[0];
    const float* logit          = (const float*)d_in[1];
    const unsigned char* paddng = (const unsigned char*)d_in[2];

    float* out     = (float*)d_out;
    float* out_pad = out + (size_t)TT * BB * DD;     // second output: (B,T) mask

    char* ws       = (char*)d_ws;
    int*   labels   = (int*)ws;                      // B*T int = 64 KiB
    int*   barriers = (int*)(ws + (1 << 16));        // 16 counters, 128B stride = 2 KiB

    // zero the per-batch barrier counters (graph-capturable async memset)
    hipMemsetAsync(barriers, 0, BB * 32 * sizeof(int), stream);
    fused_all_kernel<<<BB * NCHUNK, 256, 0, stream>>>(logit, paddng, rep,
                                                      labels, barriers, out, out_pad);
}

// Round 8
// 28.434 us; speedup vs baseline: 7.9544x; 2.9091x over previous
//
#include <hip/hip_runtime.h>
#include <cfloat>
#include <climits>

#define TT 1024
#define BB 16
#define DD 512
#define VV 1000
#define CHUNK 16         // output rows (s values) per fused block
#define NCHUNK (TT / CHUNK)
#define KROWS (CHUNK / 2)  // rows per 128-thread slot

// Kernel 1: one 64-lane wave per (t,b) position computes argmax over V logits.
// The 4 row-loads are issued explicitly back-to-back (independent, in flight
// together) before the compare tree; tail lanes get a -FLT_MAX sentinel.
__global__ void argmax_kernel(const float* __restrict__ logit, int* __restrict__ labels) {
    int gw   = (blockIdx.x * blockDim.x + threadIdx.x) >> 6;   // global wave id = t*B + b
    int lane = threadIdx.x & 63;
    const float4* row = (const float4*)(logit + (size_t)gw * VV);  // 4000B rows, 16B aligned

    // 250 float4 per row; lanes read i = lane + {0,64,128,192}; i=192+lane
    // valid only for lane<58. Clamp the address, sentinel the value.
    float4 v0 = row[lane];
    float4 v1 = row[lane + 64];
    float4 v2 = row[lane + 128];
    bool   t3 = (lane < 58);
    float4 v3 = row[t3 ? (lane + 192) : 249];      // clamped addr, masked below

    float best = -FLT_MAX;
    int   bidx = INT_MAX;
    #define ACC(vv, base)                                         \
        do {                                                      \
            if ((vv).x > best) { best = (vv).x; bidx = (base);   }\
            if ((vv).y > best) { best = (vv).y; bidx = (base)+1; }\
            if ((vv).z > best) { best = (vv).z; bidx = (base)+2; }\
            if ((vv).w > best) { best = (vv).w; bidx = (base)+3; }\
        } while (0)
    ACC(v0, lane * 4);
    ACC(v1, (lane + 64) * 4);
    ACC(v2, (lane + 128) * 4);
    if (t3) ACC(v3, (lane + 192) * 4);
    #undef ACC

    for (int off = 32; off; off >>= 1) {                // first-index tie-break
        float ov = __shfl_xor(best, off);
        int   oi = __shfl_xor(bidx, off);
        if (ov > best || (ov == best && oi < bidx)) { best = ov; bidx = oi; }
    }
    if (lane == 0) {
        int t = gw / BB, b = gw % BB;                   // logit layout is (T,B,V)
        labels[b * TT + t] = bidx;                      // store as (B,T)
    }
}

// Kernel 2: fused segmentation + compression. Block = (batch b, chunk of 16 s).
// Scan prologue builds per-batch segment structures in LDS; compress phase
// prefetches the first timestep of all 8 rows per 128-thread slot (8 loads in
// flight per wave) and falls back to a rare slow path for len>1 segments.
__global__ void __launch_bounds__(256) fused_compress_kernel(
        const int* __restrict__ labels,
        const unsigned char* __restrict__ padding,
        const float* __restrict__ rep,
        float* __restrict__ out, float* __restrict__ out_pad) {
    int b = blockIdx.x / NCHUNK;
    int c = blockIdx.x % NCHUNK;
    int tid = threadIdx.x;               // 0..255
    int lane = tid & 63, wid = tid >> 6; // 4 waves
    int t0 = tid * 4;

    __shared__ int   wtot[4];
    __shared__ int   cnt_s[TT];
    __shared__ int   start_s[TT];
    __shared__ float w_s[TT];

    // --- change flags for 4 consecutive t ---
    int4 lab4 = *(const int4*)(labels + b * TT + t0);
    int prev  = (t0 > 0) ? labels[b * TT + t0 - 1] : -1;   // raw previous label
    uchar4 p4 = *(const uchar4*)(padding + b * TT + t0);
    int v0 = !p4.x, v1 = !p4.y, v2 = !p4.z, v3 = !p4.w;
    int c0 = v0 && (lab4.x != prev);
    int c1 = v1 && (lab4.y != lab4.x);
    int c2 = v2 && (lab4.z != lab4.y);
    int c3 = v3 && (lab4.w != lab4.z);
    int l0 = c0, l1 = l0 + c1, l2 = l1 + c2, l3 = l2 + c3;  // local inclusive

    // --- wave inclusive scan of per-thread totals ---
    int x = l3;
    for (int off = 1; off < 64; off <<= 1) {
        int y = __shfl_up(x, off);
        if (lane >= off) x += y;
    }
    if (lane == 63) wtot[wid] = x;
    cnt_s[t0] = 0; cnt_s[t0 + 1] = 0; cnt_s[t0 + 2] = 0; cnt_s[t0 + 3] = 0;
    __syncthreads();
    int woff = 0;
    #pragma unroll
    for (int i = 0; i < 4; ++i) if (i < wid) woff += wtot[i];
    int ns   = wtot[0] + wtot[1] + wtot[2] + wtot[3];  // segments in batch b
    int excl = woff + x - l3;                          // exclusive prefix for t0

    int s0 = excl + l0 - 1, s1 = excl + l1 - 1, s2 = excl + l2 - 1, s3 = excl + l3 - 1;
    if (c0) start_s[s0] = t0;
    if (c1) start_s[s1] = t0 + 1;
    if (c2) start_s[s2] = t0 + 2;
    if (c3) start_s[s3] = t0 + 3;
    if (v0 && s0 >= 0) atomicAdd(&cnt_s[s0], 1);
    if (v1 && s1 >= 0) atomicAdd(&cnt_s[s1], 1);
    if (v2 && s2 >= 0) atomicAdd(&cnt_s[s2], 1);
    if (v3 && s3 >= 0) atomicAdd(&cnt_s[s3], 1);
    __syncthreads();
    w_s[t0]     = (v0 && s0 >= 0) ? (1.0f / (float)cnt_s[s0]) : 0.0f;
    w_s[t0 + 1] = (v1 && s1 >= 0) ? (1.0f / (float)cnt_s[s1]) : 0.0f;
    w_s[t0 + 2] = (v2 && s2 >= 0) ? (1.0f / (float)cnt_s[s2]) : 0.0f;
    w_s[t0 + 3] = (v3 && s3 >= 0) ? (1.0f / (float)cnt_s[s3]) : 0.0f;

    if (c == 0) {   // one chunk per batch emits the new padding mask
        float4 pm;
        pm.x = (t0     >= ns) ? 1.0f : 0.0f;
        pm.y = (t0 + 1 >= ns) ? 1.0f : 0.0f;
        pm.z = (t0 + 2 >= ns) ? 1.0f : 0.0f;
        pm.w = (t0 + 3 >= ns) ? 1.0f : 0.0f;
        *(float4*)(out_pad + b * TT + t0) = pm;
    }
    __syncthreads();

    // --- compress 16 rows: 2 slots of 128 threads, 8 rows each, ILP=8 ---
    int sub = tid >> 7;                   // row slot 0/1
    int dq  = tid & 127;                  // float4 index within D=512
    const float4* rep4 = (const float4*)rep;

    int    st[KROWS];
    int    en[KROWS];
    float4 rv[KROWS];
    bool   ok[KROWS];
    #pragma unroll
    for (int k = 0; k < KROWS; ++k) {     // issue 8 independent first-t loads
        int s = c * CHUNK + sub + 2 * k;
        ok[k] = (s < ns);
        int t1 = ok[k] ? start_s[s] : 0;
        st[k] = t1;
        en[k] = ok[k] ? ((s + 1 < ns) ? start_s[s + 1] : TT) : 0;
        if (ok[k]) rv[k] = rep4[((size_t)t1 * BB + b) * (DD / 4) + dq];
    }
    #pragma unroll
    for (int k = 0; k < KROWS; ++k) {
        int s = c * CHUNK + sub + 2 * k;
        float4 acc = make_float4(0.f, 0.f, 0.f, 0.f);
        if (ok[k]) {
            float ww = w_s[st[k]];        // segment start is always valid (w>0)
            acc.x = ww * rv[k].x; acc.y = ww * rv[k].y;
            acc.z = ww * rv[k].z; acc.w = ww * rv[k].w;
            // rare slow path: segments longer than one timestep
            for (int t = st[k] + 1; t < en[k]; ++t) {
                float w2 = w_s[t];
                if (w2 != 0.0f) {         // skips invalid (padded) timesteps
                    float4 rv2 = rep4[((size_t)t * BB + b) * (DD / 4) + dq];
                    acc.x += w2 * rv2.x; acc.y += w2 * rv2.y;
                    acc.z += w2 * rv2.z; acc.w += w2 * rv2.w;
                }
            }
        }
        ((float4*)out)[((size_t)s * BB + b) * (DD / 4) + dq] = acc;  // zeros past ns
    }
}

extern "C" void kernel_launch(void* const* d_in, const int* in_sizes, int n_in,
                              void* d_out, int out_size, void* d_ws, size_t ws_size,
                              hipStream_t stream) {
    const float* rep            = (const float*)d_in[0];
    const float* logit          = (const float*)d_in[1];
    const unsigned char* paddng = (const unsigned char*)d_in[2];

    float* out     = (float*)d_out;
    float* out_pad = out + (size_t)TT * BB * DD;     // second output: (B,T) mask

    int* labels = (int*)d_ws;                        // B*T int = 64 KiB

    argmax_kernel<<<(TT * BB) / 4, 256, 0, stream>>>(logit, labels);
    fused_compress_kernel<<<BB * NCHUNK, 256, 0, stream>>>(labels, paddng, rep, out, out_pad);
}